// Round 1
// baseline (1141.629 us; speedup 1.0000x reference)
//
#include <hip/hip_runtime.h>
#include <math.h>

#define SEQL 784
#define HIDN 512
#define BATCHN 1024
#define OUTD 10

// fast tanh: (e^{2y}-1)/(e^{2y}+1) with hardware exp + rcp (~1 ulp each).
// Clamp at +-20 (tanh(+-20) rounds to +-1 in fp32 anyway) to avoid inf/inf.
__device__ __forceinline__ float ftanh(float y) {
    y = fminf(fmaxf(y, -20.f), 20.f);
    float e = __expf(2.0f * y);
    return (e - 1.0f) * __builtin_amdgcn_rcpf(e + 1.0f);
}

// M[i][o] = sum_j C1[j][i] * W[j][o]   (512 x 10), so logits = h2f @ M + b
__global__ __launch_bounds__(64) void compute_M(const float* __restrict__ C1,
                                                const float* __restrict__ W,
                                                float* __restrict__ M) {
    __shared__ float Ws[HIDN * OUTD];
    const int i = blockIdx.x * 64 + threadIdx.x;
    for (int idx = threadIdx.x; idx < HIDN * OUTD; idx += 64) Ws[idx] = W[idx];
    __syncthreads();
    float acc[OUTD];
#pragma unroll
    for (int o = 0; o < OUTD; ++o) acc[o] = 0.f;
    for (int j = 0; j < HIDN; ++j) {
        float cv = C1[j * HIDN + i];  // coalesced across lanes
#pragma unroll
        for (int o = 0; o < OUTD; ++o) acc[o] += cv * Ws[j * OUTD + o];  // LDS broadcast
    }
#pragma unroll
    for (int o = 0; o < OUTD; ++o) M[i * OUTD + o] = acc[o];
}

// One wave (64 lanes) per batch row; lane owns 8 contiguous hidden elems.
// Per step (both layers pipelined, layer2 lags by 1 step):
//   w = (I + cA)h + (u/L) P      via prefix sum of P*h   (A = diag(n) - tril(P P^T))
//   solve (I - cA) y = w         via affine scan: s_i = a_i s_{i-1} + (P_i/d_i) w_i,
//                                y_i = (w_i - c P_i s_{i-1}) / d_i,  d_i = 1 + c(1+i)
//   h <- tanh(y)
// This is algebraically exactly A_d h + u B_d of the reference (bilinear HiPPO).
__global__ __launch_bounds__(256) void ssm_main(const float* __restrict__ x,
                                                const float* __restrict__ C0,
                                                const float* __restrict__ Mmat,
                                                const float* __restrict__ bias,
                                                float* __restrict__ out) {
    const int tid = threadIdx.x;
    const int wave = tid >> 6;
    const int lane = tid & 63;
    const int row = blockIdx.x * 4 + wave;

    __shared__ float xs[4][SEQL];
    __shared__ float Ms[HIDN * OUTD];

    // stage the 4 rows of x for this block (contiguous, coalesced)
    for (int idx = tid; idx < 4 * SEQL; idx += 256)
        xs[idx / SEQL][idx % SEQL] = x[blockIdx.x * 4 * SEQL + idx];
    __syncthreads();

    // per-lane closed-form constants (double precision -> fp32, like the reference's
    // float64 A_d/B_d construction cast to float32)
    const double cd = 1.0 / 1568.0;   // step/2
    float P[8], cP[8], g[8], av[8], kf[8], fv[8], C0v[8];
    double Aprod = 1.0;
#pragma unroll
    for (int j = 0; j < 8; ++j) {
        int i = lane * 8 + j;
        double Pd = sqrt(1.0 + 2.0 * (double)i);
        double dd = 1.0 + cd * (1.0 + (double)i);
        double fd = 1.0 / dd;
        double ad = (1.0 - cd * (double)i) * fd;
        P[j] = (float)Pd;
        cP[j] = (float)(cd * Pd);
        g[j] = (float)(1.0 + cd * (double)i);
        av[j] = (float)ad;
        kf[j] = (float)(Pd * fd);
        fv[j] = (float)fd;
        Aprod *= ad;
        C0v[j] = C0[i];
    }
    const float Aloc = (float)Aprod;  // product of this lane's a_j (scan seed)
    const float DEL = 1.0f / 784.0f;

    float h[2][8];
#pragma unroll
    for (int j = 0; j < 8; ++j) { h[0][j] = 0.f; h[1][j] = 0.f; }

    float y0 = 0.f;              // layer-2 input (lags one step; 0 at k=0 keeps h2==0)
    float u1 = xs[wave][0];

    for (int k = 0; k < SEQL + 1; ++k) {
        // prefetch next step's scalar input (broadcast LDS read)
        float u_next = xs[wave][(k + 1 < SEQL) ? (k + 1) : (SEQL - 1)];
        float du[2] = { DEL * u1, DEL * y0 };

        // ---- inclusive prefix of P .* h (per-lane serial, both chains interleaved)
        float pv[2][8];
        float run0 = 0.f, run1 = 0.f;
#pragma unroll
        for (int j = 0; j < 8; ++j) {
            run0 += P[j] * h[0][j]; pv[0][j] = run0;
            run1 += P[j] * h[1][j]; pv[1][j] = run1;
        }
        // wave-level exclusive sum of lane totals
        float s0 = run0, s1 = run1;
#pragma unroll
        for (int d = 1; d < 64; d <<= 1) {
            float o0 = __shfl_up(s0, d, 64);
            float o1 = __shfl_up(s1, d, 64);
            if (lane >= d) { s0 += o0; s1 += o1; }
        }
        float e0 = __shfl_up(s0, 1, 64);
        float e1 = __shfl_up(s1, 1, 64);
        float base[2];
        base[0] = lane ? e0 : 0.f;
        base[1] = lane ? e1 : 0.f;

        // ---- w = g*h - cP*(prefix) + (u/L)*P ; per-lane affine compose
        float w[2][8], kw[2][8];
        float B0 = 0.f, B1 = 0.f;
#pragma unroll
        for (int j = 0; j < 8; ++j) {
            float w0 = g[j] * h[0][j] - cP[j] * (base[0] + pv[0][j]) + du[0] * P[j];
            float w1 = g[j] * h[1][j] - cP[j] * (base[1] + pv[1][j]) + du[1] * P[j];
            w[0][j] = w0; w[1][j] = w1;
            float k0 = kf[j] * w0, k1 = kf[j] * w1;
            kw[0][j] = k0; kw[1][j] = k1;
            B0 = av[j] * B0 + k0;
            B1 = av[j] * B1 + k1;
        }
        // wave-level exclusive affine scan: T = (A,B), compose cur o prev
        float A0 = Aloc, A1 = Aloc;
#pragma unroll
        for (int d = 1; d < 64; d <<= 1) {
            float pA0 = __shfl_up(A0, d, 64), pB0 = __shfl_up(B0, d, 64);
            float pA1 = __shfl_up(A1, d, 64), pB1 = __shfl_up(B1, d, 64);
            if (lane >= d) {
                B0 = A0 * pB0 + B0; A0 *= pA0;
                B1 = A1 * pB1 + B1; A1 *= pA1;
            }
        }
        float sB0 = __shfl_up(B0, 1, 64);
        float sB1 = __shfl_up(B1, 1, 64);
        float sA = lane ? sB0 : 0.f;   // scan state entering this lane, chain 0
        float sB = lane ? sB1 : 0.f;   // chain 1

        // ---- forward substitution within lane + tanh
#pragma unroll
        for (int j = 0; j < 8; ++j) {
            float yA = (w[0][j] - cP[j] * sA) * fv[j];
            float yB = (w[1][j] - cP[j] * sB) * fv[j];
            sA = av[j] * sA + kw[0][j];
            sB = av[j] * sB + kw[1][j];
            h[0][j] = ftanh(yA);
            h[1][j] = ftanh(yB);
        }

        // ---- y0 = C0 . h1_new (wave butterfly reduce)
        float part = 0.f;
#pragma unroll
        for (int j = 0; j < 8; ++j) part += C0v[j] * h[0][j];
#pragma unroll
        for (int d = 32; d; d >>= 1) part += __shfl_xor(part, d, 64);
        y0 = part;
        u1 = u_next;
    }

    // ---- epilogue: logits[row] = h2_final @ M + b
    __syncthreads();
    for (int idx = tid; idx < HIDN * OUTD; idx += 256) Ms[idx] = Mmat[idx];
    __syncthreads();

    float acc[OUTD];
#pragma unroll
    for (int o = 0; o < OUTD; ++o) acc[o] = 0.f;
#pragma unroll
    for (int j = 0; j < 8; ++j) {
        float hv = h[1][j];
        int i = lane * 8 + j;
#pragma unroll
        for (int o = 0; o < OUTD; ++o) acc[o] += hv * Ms[i * OUTD + o];
    }
#pragma unroll
    for (int o = 0; o < OUTD; ++o) {
#pragma unroll
        for (int d = 32; d; d >>= 1) acc[o] += __shfl_xor(acc[o], d, 64);
    }
    if (lane == 0) {
#pragma unroll
        for (int o = 0; o < OUTD; ++o) out[row * OUTD + o] = acc[o] + bias[o];
    }
}

extern "C" void kernel_launch(void* const* d_in, const int* in_sizes, int n_in,
                              void* d_out, int out_size, void* d_ws, size_t ws_size,
                              hipStream_t stream) {
    const float* x  = (const float*)d_in[0];  // (1024, 784)
    const float* C0 = (const float*)d_in[1];  // (1, 512)
    const float* C1 = (const float*)d_in[2];  // (512, 512)
    const float* W  = (const float*)d_in[3];  // (512, 10)
    const float* b  = (const float*)d_in[4];  // (10,)
    float* M = (float*)d_ws;                  // 512*10 fp32 = 20 KB scratch

    compute_M<<<dim3(8), dim3(64), 0, stream>>>(C1, W, M);
    ssm_main<<<dim3(256), dim3(256), 0, stream>>>(x, C0, M, b, (float*)d_out);
}

// Round 2
// 764.796 us; speedup vs baseline: 1.4927x; 1.4927x over previous
//
#include <hip/hip_runtime.h>
#include <math.h>

#define SEQL 784
#define HIDN 512
#define OUTD 10

// DPP mov: returns src shifted per CTRL; invalid/masked lanes yield 0.
template<int CTRL, int RM>
__device__ __forceinline__ float dpp0(float v) {
    int r = __builtin_amdgcn_update_dpp(0, __builtin_bit_cast(int, v),
                                        CTRL, RM, 0xF, true);
    return __builtin_bit_cast(float, r);
}

// tanh = 1 - 2/(e^{2y}+1); inf-safe (e=inf -> rcp=0 -> 1; e=0 -> -1).
__device__ __forceinline__ float ftanh(float y) {
    float e = __expf(y + y);
    return fmaf(-2.0f, __builtin_amdgcn_rcpf(e + 1.0f), 1.0f);
}

// M[i][o] = sum_j C1[j][i] * W[j][o]   (512 x 10), so logits = h2f @ M + b
__global__ __launch_bounds__(64) void compute_M(const float* __restrict__ C1,
                                                const float* __restrict__ W,
                                                float* __restrict__ M) {
    __shared__ float Ws[HIDN * OUTD];
    const int i = blockIdx.x * 64 + threadIdx.x;
    for (int idx = threadIdx.x; idx < HIDN * OUTD; idx += 64) Ws[idx] = W[idx];
    __syncthreads();
    float acc[OUTD];
#pragma unroll
    for (int o = 0; o < OUTD; ++o) acc[o] = 0.f;
    for (int j = 0; j < HIDN; ++j) {
        float cv = C1[j * HIDN + i];
#pragma unroll
        for (int o = 0; o < OUTD; ++o) acc[o] += cv * Ws[j * OUTD + o];
    }
#pragma unroll
    for (int o = 0; o < OUTD; ++o) M[i * OUTD + o] = acc[o];
}

// One wave per batch row; lane owns 8 contiguous hidden elems. Per step the
// whole update h <- tanh(A_d h + u B_d) is ONE affine scan over the 2-state
// (r = prefix of P.h, s = solve state of (I-cA)):
//   r_i = r_{i-1} + P_i h_i
//   s_i = a_i s_{i-1} + e_i r_{i-1} + (q_i h_i + t_i du)
//   y_i = G_i h_i + T_i du - E_i (r_{i-1} + s_{i-1})
// Matrices [[1,0],[e_i,a_i]] are data-independent -> all scan multipliers are
// precomputed constants; wave scan done with DPP (VALU), not ds_bpermute.
__global__ __launch_bounds__(256, 1) void ssm_main(const float* __restrict__ x,
                                                   const float* __restrict__ C0,
                                                   const float* __restrict__ Mmat,
                                                   const float* __restrict__ bias,
                                                   float* __restrict__ out) {
    const int tid = threadIdx.x;
    const int wave = tid >> 6;
    const int lane = tid & 63;
    const int row = blockIdx.x * 4 + wave;

    __shared__ float xs[4][SEQL];
    __shared__ float Ms[HIDN * OUTD];

    for (int idx = tid; idx < 4 * SEQL; idx += 256)
        xs[idx / SEQL][idx % SEQL] = x[blockIdx.x * 4 * SEQL + idx];
    __syncthreads();

    // ---- per-lane constants (fp64 -> fp32, matching reference's f64 discretization)
    const double cd = 1.0 / 1568.0;  // step/2
    float P[8], a_[8], e_[8], q_[8], t_[8], G_[8], T_[8], mE[8], ap1[8], bp[8], C0v[8];
    double apD = 0.0, bpD = 1.0;  // running in-lane partial (alpha, beta)
#pragma unroll
    for (int j = 0; j < 8; ++j) {
        int i = lane * 8 + j;
        double Pd = sqrt(1.0 + 2.0 * (double)i);
        double dd = 1.0 + cd * (double)(i + 1);
        double fd = 1.0 / dd;
        double ad = (1.0 - cd * (double)i) * fd;   // (1-ci)/d
        double Td = Pd * fd;                        // P/d
        double td = Pd * Pd * fd;                   // P^2/d
        double ed = -cd * td;                       // -cP^2/d
        double gc = 1.0 - cd * (double)(i + 1);     // g - cP^2
        ap1[j] = (float)(1.0 + apD);                // 1 + alpha_part(before elem j)
        bp[j]  = (float)bpD;                        // beta_part(before elem j)
        apD = ad * apD + ed;
        bpD = ad * bpD;
        P[j]  = (float)Pd;  a_[j] = (float)ad;  e_[j] = (float)ed;
        q_[j] = (float)(Td * gc);  t_[j] = (float)td;
        G_[j] = (float)(gc * fd);  T_[j] = (float)Td;
        mE[j] = (float)(-cd * Pd * fd);             // -cP/d
        C0v[j] = C0[i];
    }
    // ---- scan-level constants: mirror the DPP segment structure exactly
    float ac[6], bc[6];
    {
        double al = apD, be = bpD;  // lane-aggregate (alpha, beta)
        int rl = lane & 15;
#pragma unroll
        for (int L = 0; L < 4; ++L) {          // row_shr:1,2,4,8 (row-capped)
            int d = 1 << L;
            ac[L] = (float)al; bc[L] = (float)be;
            double pa = __shfl_up(al, d, 64);
            double pb = __shfl_up(be, d, 64);
            if (rl >= d) { al += be * pa; be *= pb; }
        }
        ac[4] = (float)al; bc[4] = (float)be;  // row_bcast:15 (rows 1,3 <- lane 15/47)
        {
            int src = (lane & 32) + 15;
            double pa = __shfl(al, src, 64);
            double pb = __shfl(be, src, 64);
            if (lane & 16) { al += be * pa; be *= pb; }
        }
        ac[5] = (float)al; bc[5] = (float)be;  // row_bcast:31 (rows 2,3 <- lane 31)
        {
            double pa = __shfl(al, 31, 64);
            double pb = __shfl(be, 31, 64);
            if (lane >= 32) { al += be * pa; be *= pb; }
        }
    }

    const float DEL = 1.0f / 784.0f;
    float h[2][8];
#pragma unroll
    for (int j = 0; j < 8; ++j) { h[0][j] = 0.f; h[1][j] = 0.f; }

    float y0 = 0.f;               // layer-2 input (1-step lag; 0 keeps h2 == 0)
    float u1 = xs[wave][0];

    for (int k = 0; k < SEQL + 1; ++k) {
        float u_next = xs[wave][(k + 1 < SEQL) ? (k + 1) : (SEQL - 1)];
        float du0 = DEL * u1, du1 = DEL * y0;

        // ---- pass 1: per-lane local (r,s) + saved per-elem terms
        float g0[8], g1[8], m0[8], m1[8];
        float r0 = 0.f, s0 = 0.f, r1 = 0.f, s1 = 0.f;
#pragma unroll
        for (int j = 0; j < 8; ++j) {
            float h0j = h[0][j], h1j = h[1][j];
            float z0 = fmaf(q_[j], h0j, t_[j] * du0);
            float z1 = fmaf(q_[j], h1j, t_[j] * du1);
            g0[j] = fmaf(G_[j], h0j, T_[j] * du0);
            g1[j] = fmaf(G_[j], h1j, T_[j] * du1);
            m0[j] = r0 + s0;
            m1[j] = r1 + s1;
            s0 = fmaf(a_[j], s0, fmaf(e_[j], r0, z0));
            s1 = fmaf(a_[j], s1, fmaf(e_[j], r1, z1));
            r0 = fmaf(P[j], h0j, r0);
            r1 = fmaf(P[j], h1j, r1);
        }

        // ---- wave-level affine scan via DPP (pure VALU)
#define LVL(CTRL, RM, L) {                              \
        float r0s = dpp0<CTRL, RM>(r0);                 \
        float s0s = dpp0<CTRL, RM>(s0);                 \
        float r1s = dpp0<CTRL, RM>(r1);                 \
        float s1s = dpp0<CTRL, RM>(s1);                 \
        s0 = fmaf(bc[L], s0s, fmaf(ac[L], r0s, s0));    \
        s1 = fmaf(bc[L], s1s, fmaf(ac[L], r1s, s1));    \
        r0 += r0s; r1 += r1s; }
        LVL(0x111, 0xF, 0)   // row_shr:1
        LVL(0x112, 0xF, 1)   // row_shr:2
        LVL(0x114, 0xF, 2)   // row_shr:4
        LVL(0x118, 0xF, 3)   // row_shr:8
        LVL(0x142, 0xA, 4)   // row_bcast:15 -> rows 1,3
        LVL(0x143, 0xC, 5)   // row_bcast:31 -> rows 2,3
#undef LVL
        // exclusive: state entering this lane (lane 0 -> 0)
        float ri0 = dpp0<0x138, 0xF>(r0), si0 = dpp0<0x138, 0xF>(s0);  // wave_shr:1
        float ri1 = dpp0<0x138, 0xF>(r1), si1 = dpp0<0x138, 0xF>(s1);

        // ---- pass 2: fully parallel reconstruction + tanh
        float part = 0.f;
#pragma unroll
        for (int j = 0; j < 8; ++j) {
            float mm0 = fmaf(bp[j], si0, fmaf(ap1[j], ri0, m0[j]));
            float mm1 = fmaf(bp[j], si1, fmaf(ap1[j], ri1, m1[j]));
            float yy0 = fmaf(mE[j], mm0, g0[j]);
            float yy1 = fmaf(mE[j], mm1, g1[j]);
            float hn0 = ftanh(yy0);
            float hn1 = ftanh(yy1);
            h[0][j] = hn0; h[1][j] = hn1;
            part = fmaf(C0v[j], hn0, part);
        }
        // y0 = C0 . h1_new — off critical path (consumed next iteration)
#pragma unroll
        for (int d = 32; d; d >>= 1) part += __shfl_xor(part, d, 64);
        y0 = part;
        u1 = u_next;
    }

    // ---- epilogue: logits[row] = h2_final @ M + b
    __syncthreads();
    for (int idx = tid; idx < HIDN * OUTD; idx += 256) Ms[idx] = Mmat[idx];
    __syncthreads();

    float acc[OUTD];
#pragma unroll
    for (int o = 0; o < OUTD; ++o) acc[o] = 0.f;
#pragma unroll
    for (int j = 0; j < 8; ++j) {
        float hv = h[1][j];
        int i = lane * 8 + j;
#pragma unroll
        for (int o = 0; o < OUTD; ++o) acc[o] += hv * Ms[i * OUTD + o];
    }
#pragma unroll
    for (int o = 0; o < OUTD; ++o) {
#pragma unroll
        for (int d = 32; d; d >>= 1) acc[o] += __shfl_xor(acc[o], d, 64);
    }
    if (lane == 0) {
#pragma unroll
        for (int o = 0; o < OUTD; ++o) out[row * OUTD + o] = acc[o] + bias[o];
    }
}

extern "C" void kernel_launch(void* const* d_in, const int* in_sizes, int n_in,
                              void* d_out, int out_size, void* d_ws, size_t ws_size,
                              hipStream_t stream) {
    const float* x  = (const float*)d_in[0];  // (1024, 784)
    const float* C0 = (const float*)d_in[1];  // (1, 512)
    const float* C1 = (const float*)d_in[2];  // (512, 512)
    const float* W  = (const float*)d_in[3];  // (512, 10)
    const float* b  = (const float*)d_in[4];  // (10,)
    float* M = (float*)d_ws;                  // 512*10 fp32 scratch

    compute_M<<<dim3(8), dim3(64), 0, stream>>>(C1, W, M);
    ssm_main<<<dim3(256), dim3(256), 0, stream>>>(x, C0, M, b, (float*)d_out);
}

// Round 3
// 497.514 us; speedup vs baseline: 2.2947x; 1.5372x over previous
//
#include <hip/hip_runtime.h>
#include <math.h>

#define SEQL 784
#define HIDN 512
#define OUTD 10

typedef float v2 __attribute__((ext_vector_type(2)));

// DPP mov: returns src moved per CTRL; lanes not written (row_mask) or with
// invalid source (bound_ctrl) yield 0.
template<int CTRL, int RM>
__device__ __forceinline__ float dpp0(float v) {
    int r = __builtin_amdgcn_update_dpp(0, __builtin_bit_cast(int, v),
                                        CTRL, RM, 0xF, true);
    return __builtin_bit_cast(float, r);
}
template<int CTRL, int RM>
__device__ __forceinline__ v2 dpp2(v2 v) {
    v2 r; r.x = dpp0<CTRL, RM>(v.x); r.y = dpp0<CTRL, RM>(v.y); return r;
}
__device__ __forceinline__ v2 sp(float v) { v2 r; r.x = v; r.y = v; return r; }
__device__ __forceinline__ v2 vfma(v2 a, v2 b, v2 c) {
    return __builtin_elementwise_fma(a, b, c);   // -> v_pk_fma_f32
}

// M[i][o] = sum_j C1[j][i] * W[j][o]  (512 x 10): logits = h2f @ M + b.
// 8 blocks x 256; each wave covers 128 j's, LDS cross-wave reduce.
__global__ __launch_bounds__(256) void compute_M(const float* __restrict__ C1,
                                                 const float* __restrict__ W,
                                                 float* __restrict__ M) {
    __shared__ float Ws[HIDN * OUTD];
    __shared__ float red[4][64][OUTD];
    const int lane = threadIdx.x & 63, w = threadIdx.x >> 6;
    const int i = blockIdx.x * 64 + lane;
    for (int idx = threadIdx.x; idx < HIDN * OUTD; idx += 256) Ws[idx] = W[idx];
    __syncthreads();
    float acc[OUTD];
#pragma unroll
    for (int o = 0; o < OUTD; ++o) acc[o] = 0.f;
    for (int j = w * 128; j < w * 128 + 128; ++j) {
        float cv = C1[j * HIDN + i];
#pragma unroll
        for (int o = 0; o < OUTD; ++o) acc[o] = fmaf(cv, Ws[j * OUTD + o], acc[o]);
    }
#pragma unroll
    for (int o = 0; o < OUTD; ++o) red[w][lane][o] = acc[o];
    __syncthreads();
    if (w == 0) {
#pragma unroll
        for (int o = 0; o < OUTD; ++o)
            M[i * OUTD + o] = (red[0][lane][o] + red[1][lane][o]) +
                              (red[2][lane][o] + red[3][lane][o]);
    }
}

// One wave per batch row; lane owns 8 hidden elems; the two pipelined layers
// (layer2 lags 1 step) ride in .x/.y of packed-fp32 registers. Per step, the
// update h <- tanh(A_d h + u B_d) is ONE affine scan over (r = prefix P.h,
// s = solve state of (I-cA)), with data-independent 2x2 scan matrices ->
// all multipliers are precomputed constants; scan runs on DPP (pure VALU).
__global__ __launch_bounds__(256, 1) void ssm_main(const float* __restrict__ x,
                                                   const float* __restrict__ C0,
                                                   const float* __restrict__ Mmat,
                                                   const float* __restrict__ bias,
                                                   float* __restrict__ out) {
    const int tid = threadIdx.x;
    const int wave = tid >> 6;
    const int lane = tid & 63;
    const int row = blockIdx.x * 4 + wave;

    __shared__ float xs[4][SEQL];
    __shared__ float Ms[HIDN * OUTD];

    for (int idx = tid; idx < 4 * SEQL; idx += 256)
        xs[idx / SEQL][idx % SEQL] = x[blockIdx.x * 4 * SEQL + idx];
    __syncthreads();

    // ---- per-lane constants (fp64 -> fp32, matching reference's f64 A_d/B_d)
    // folded set: z-term and e-term satisfy  e*r + z = P * fma(mE, r, g)
    const double cd = 1.0 / 1568.0;  // step/2
    float P[8], a_[8], G_[8], T_[8], mE[8], ap1[8], bp[8], C0v[8];
    double apD = 0.0, bpD = 1.0;     // in-lane partial (alpha, beta)
#pragma unroll
    for (int j = 0; j < 8; ++j) {
        int i = lane * 8 + j;
        double Pd = sqrt(1.0 + 2.0 * (double)i);
        double dd = 1.0 + cd * (double)(i + 1);
        double fd = 1.0 / dd;
        double ad = (1.0 - cd * (double)i) * fd;
        double ed = -cd * Pd * Pd * fd;
        double gc = 1.0 - cd * (double)(i + 1);
        ap1[j] = (float)(1.0 + apD);
        bp[j]  = (float)bpD;
        apD = ad * apD + ed;
        bpD = ad * bpD;
        P[j]  = (float)Pd;
        a_[j] = (float)ad;
        G_[j] = (float)(gc * fd);
        T_[j] = (float)(Pd * fd);
        mE[j] = (float)(-cd * Pd * fd);
        C0v[j] = C0[i];
    }
    // ---- scan-level constants mirroring the DPP segment structure
    float ac[6], bc[6];
    {
        double al = apD, be = bpD;
        int rl = lane & 15;
#pragma unroll
        for (int L = 0; L < 4; ++L) {          // row_shr:1,2,4,8 (row-capped)
            int d = 1 << L;
            ac[L] = (float)al; bc[L] = (float)be;
            double pa = __shfl_up(al, d, 64);
            double pb = __shfl_up(be, d, 64);
            if (rl >= d) { al += be * pa; be *= pb; }
        }
        ac[4] = (float)al; bc[4] = (float)be;  // row_bcast:15 -> rows 1,3
        {
            int src = (lane & 32) + 15;
            double pa = __shfl(al, src, 64);
            double pb = __shfl(be, src, 64);
            if (lane & 16) { al += be * pa; be *= pb; }
        }
        ac[5] = (float)al; bc[5] = (float)be;  // row_bcast:31 -> rows 2,3
        {
            double pa = __shfl(al, 31, 64);
            double pb = __shfl(be, 31, 64);
            if (lane >= 32) { al += be * pa; be *= pb; }
        }
    }

    const float DEL = 1.0f / 784.0f;
    v2 h[8];
#pragma unroll
    for (int j = 0; j < 8; ++j) h[j] = sp(0.f);

    float y0s = 0.f;              // layer-2 input (1-step lag; 0 keeps h2 == 0)
    float u1 = xs[wave][0];

    for (int k = 0; k < SEQL + 1; ++k) {
        float u_next = xs[wave][(k + 1 < SEQL) ? (k + 1) : (SEQL - 1)];
        v2 du; du.x = DEL * u1; du.y = DEL * y0s;

        // ---- pass 1: per-lane local (r,s), saved per-elem g,m (packed)
        v2 g[8], m[8];
        v2 r = sp(0.f), s = sp(0.f);
#pragma unroll
        for (int j = 0; j < 8; ++j) {
            v2 hj = h[j];
            v2 Tdu = sp(T_[j]) * du;
            v2 gj = vfma(sp(G_[j]), hj, Tdu);     // g = G h + T du
            g[j] = gj;
            m[j] = r + s;
            v2 inner = vfma(sp(mE[j]), r, gj);    // e r + z = P*(mE r + g)
            s = vfma(sp(a_[j]), s, sp(P[j]) * inner);
            r = vfma(sp(P[j]), hj, r);
        }

        // ---- wave-level affine scan via DPP (packed state, pure VALU)
#define LVL(CTRL, RM, L) {                                  \
        v2 rs = dpp2<CTRL, RM>(r);                          \
        v2 ss = dpp2<CTRL, RM>(s);                          \
        s = vfma(sp(bc[L]), ss, vfma(sp(ac[L]), rs, s));    \
        r += rs; }
        LVL(0x111, 0xF, 0)   // row_shr:1
        LVL(0x112, 0xF, 1)   // row_shr:2
        LVL(0x114, 0xF, 2)   // row_shr:4
        LVL(0x118, 0xF, 3)   // row_shr:8
        LVL(0x142, 0xA, 4)   // row_bcast:15 -> rows 1,3
        LVL(0x143, 0xC, 5)   // row_bcast:31 -> rows 2,3
#undef LVL
        v2 ri = dpp2<0x138, 0xF>(r);   // wave_shr:1 -> exclusive (lane0 = 0)
        v2 si = dpp2<0x138, 0xF>(s);

        // ---- pass 2: parallel reconstruction + tanh (packed; exp/rcp scalar)
        float part = 0.f;
#pragma unroll
        for (int j = 0; j < 8; ++j) {
            v2 mm = vfma(sp(bp[j]), si, vfma(sp(ap1[j]), ri, m[j]));
            v2 yy = vfma(sp(mE[j]), mm, g[j]);
            v2 y2 = yy + yy;
            v2 e; e.x = __expf(y2.x); e.y = __expf(y2.y);
            v2 e1 = e + sp(1.f);
            v2 rc; rc.x = __builtin_amdgcn_rcpf(e1.x);
            rc.y = __builtin_amdgcn_rcpf(e1.y);
            v2 hn = vfma(sp(-2.f), rc, sp(1.f));   // tanh = 1 - 2/(e^{2y}+1)
            h[j] = hn;
            part = fmaf(C0v[j], hn.x, part);
        }
        // y0 = C0 . h1_new : DPP reduce to lane 63 -> readlane -> SGPR bcast
        part += dpp0<0x111, 0xF>(part);
        part += dpp0<0x112, 0xF>(part);
        part += dpp0<0x114, 0xF>(part);
        part += dpp0<0x118, 0xF>(part);
        part += dpp0<0x142, 0xA>(part);
        part += dpp0<0x143, 0xC>(part);
        y0s = __builtin_bit_cast(float,
                __builtin_amdgcn_readlane(__builtin_bit_cast(int, part), 63));
        u1 = u_next;
    }

    // ---- epilogue: logits[row] = h2_final @ M + b
    __syncthreads();
    for (int idx = tid; idx < HIDN * OUTD; idx += 256) Ms[idx] = Mmat[idx];
    __syncthreads();

    float acc[OUTD];
#pragma unroll
    for (int o = 0; o < OUTD; ++o) acc[o] = 0.f;
#pragma unroll
    for (int j = 0; j < 8; ++j) {
        float hv = h[j].y;
        int i = lane * 8 + j;
#pragma unroll
        for (int o = 0; o < OUTD; ++o) acc[o] = fmaf(hv, Ms[i * OUTD + o], acc[o]);
    }
#pragma unroll
    for (int o = 0; o < OUTD; ++o) {
#pragma unroll
        for (int d = 32; d; d >>= 1) acc[o] += __shfl_xor(acc[o], d, 64);
    }
    if (lane == 0) {
#pragma unroll
        for (int o = 0; o < OUTD; ++o) out[row * OUTD + o] = acc[o] + bias[o];
    }
}

extern "C" void kernel_launch(void* const* d_in, const int* in_sizes, int n_in,
                              void* d_out, int out_size, void* d_ws, size_t ws_size,
                              hipStream_t stream) {
    const float* x  = (const float*)d_in[0];  // (1024, 784)
    const float* C0 = (const float*)d_in[1];  // (1, 512)
    const float* C1 = (const float*)d_in[2];  // (512, 512)
    const float* W  = (const float*)d_in[3];  // (512, 10)
    const float* b  = (const float*)d_in[4];  // (10,)
    float* M = (float*)d_ws;                  // 512*10 fp32 scratch

    compute_M<<<dim3(8), dim3(256), 0, stream>>>(C1, W, M);
    ssm_main<<<dim3(256), dim3(256), 0, stream>>>(x, C0, M, b, (float*)d_out);
}

// Round 4
// 430.001 us; speedup vs baseline: 2.6549x; 1.1570x over previous
//
#include <hip/hip_runtime.h>
#include <math.h>

#define SEQL 784
#define HIDN 512
#define OUTD 10

typedef float v2 __attribute__((ext_vector_type(2)));

// DPP mov: lanes not selected by row_mask, or with invalid source (bound_ctrl),
// yield `old` = 0. Single-use results are foldable into v_{add,fmac}_f32_dpp.
template<int CTRL, int RM>
__device__ __forceinline__ float dpp0(float v) {
    int r = __builtin_amdgcn_update_dpp(0, __builtin_bit_cast(int, v),
                                        CTRL, RM, 0xF, true);
    return __builtin_bit_cast(float, r);
}
__device__ __forceinline__ v2 sp(float v) { v2 r; r.x = v; r.y = v; return r; }
__device__ __forceinline__ v2 vfma(v2 a, v2 b, v2 c) {
    return __builtin_elementwise_fma(a, b, c);   // -> v_pk_fma_f32
}

// M[i][o] = sum_j C1[j][i] * W[j][o]  (512 x 10): logits = h2f @ M + b.
__global__ __launch_bounds__(256) void compute_M(const float* __restrict__ C1,
                                                 const float* __restrict__ W,
                                                 float* __restrict__ M) {
    __shared__ float Ws[HIDN * OUTD];
    __shared__ float red[4][64][OUTD];
    const int lane = threadIdx.x & 63, w = threadIdx.x >> 6;
    const int i = blockIdx.x * 64 + lane;
    for (int idx = threadIdx.x; idx < HIDN * OUTD; idx += 256) Ws[idx] = W[idx];
    __syncthreads();
    float acc[OUTD];
#pragma unroll
    for (int o = 0; o < OUTD; ++o) acc[o] = 0.f;
    for (int j = w * 128; j < w * 128 + 128; ++j) {
        float cv = C1[j * HIDN + i];
#pragma unroll
        for (int o = 0; o < OUTD; ++o) acc[o] = fmaf(cv, Ws[j * OUTD + o], acc[o]);
    }
#pragma unroll
    for (int o = 0; o < OUTD; ++o) red[w][lane][o] = acc[o];
    __syncthreads();
    if (w == 0) {
#pragma unroll
        for (int o = 0; o < OUTD; ++o)
            M[i * OUTD + o] = (red[0][lane][o] + red[1][lane][o]) +
                              (red[2][lane][o] + red[3][lane][o]);
    }
}

// One wave per batch row; lane owns 8 hidden elems; layers 1/2 (layer2 lags one
// step) ride in .x/.y of packed fp32. Per step: h <- tanh(solve((I+cA)h) + du*Bd)
// via ONE affine scan over (r = prefix P.h, s = solve state); du is injected in
// pass 2 only (Bd = (I-cA)^-1 P precomputed), so the y0 reduce has a full step
// of slack. exp2-scaling (2*log2e) folded into pass-2 constants.
__global__ __launch_bounds__(256, 1) void ssm_main(const float* __restrict__ x,
                                                   const float* __restrict__ C0,
                                                   const float* __restrict__ Mmat,
                                                   const float* __restrict__ bias,
                                                   float* __restrict__ out) {
    const int tid = threadIdx.x;
    const int wave = tid >> 6;
    const int lane = tid & 63;
    const int row = blockIdx.x * 4 + wave;

    __shared__ float xs[4][SEQL + 2];
    __shared__ float Ms[HIDN * OUTD];

    const float DEL = 1.0f / 784.0f;
    for (int idx = tid; idx < 4 * SEQL; idx += 256)
        xs[idx / SEQL][idx % SEQL] = DEL * x[blockIdx.x * 4 * SEQL + idx];
    if (tid < 8) xs[tid >> 1][SEQL + (tid & 1)] = 0.f;
    __syncthreads();

    // ---- per-lane constants (fp64 -> fp32, matching reference f64 A_d/B_d)
    const double cd = 1.0 / 1568.0;            // step/2
    const double F = 2.0 * 1.4426950408889634; // 2*log2(e) fold for exp2
    float P[8], Ps[8], a_[8], G2[8], mE2[8], K1[8], K2[8], Bd2[8], C0d[8];
    double apD = 0.0, bpD = 1.0;               // in-lane partial (alpha, beta)
    double aL = 1.0, bL = 0.0;                 // lane-local Bd-solve affine
#pragma unroll
    for (int j = 0; j < 8; ++j) {
        int i = lane * 8 + j;
        double Pd = sqrt(1.0 + 2.0 * (double)i);
        double dd = 1.0 + cd * (double)(i + 1);
        double fd = 1.0 / dd;
        double ad = (1.0 - cd * (double)i) * fd;
        double mEd = -cd * Pd * fd;
        double ed = Pd * mEd;                   // -cP^2/d
        double Gd = (1.0 - cd * (double)(i + 1)) * fd;
        K2[j] = (float)(F * mEd * (1.0 + apD));
        K1[j] = (float)(F * mEd * bpD);
        apD = ad * apD + ed;
        bpD = ad * bpD;
        P[j]   = (float)Pd;
        Ps[j]  = (float)(Pd / F);
        a_[j]  = (float)ad;
        G2[j]  = (float)(F * Gd);
        mE2[j] = (float)(F * mEd);
        C0d[j] = DEL * C0[i];
        // Bd-solve lane-local affine accumulation: s_i = a_i s + P_i^2 f_i
        bL = ad * bL + Pd * Pd * fd;
        aL *= ad;
    }
    // ---- scan-level constants mirroring the DPP segment structure (unscaled)
    float ac[6], bc[6];
    {
        double al = apD, be = bpD;
        int rl = lane & 15;
#pragma unroll
        for (int L = 0; L < 4; ++L) {          // row_shr:1,2,4,8 (row-capped)
            int d = 1 << L;
            ac[L] = (float)al; bc[L] = (float)be;
            double pa = __shfl_up(al, d, 64);
            double pb = __shfl_up(be, d, 64);
            if (rl >= d) { al += be * pa; be *= pb; }
        }
        ac[4] = (float)al; bc[4] = (float)be;  // row_bcast:15 -> rows 1,3
        {
            int src = (lane & 32) + 15;
            double pa = __shfl(al, src, 64);
            double pb = __shfl(be, src, 64);
            if (lane & 16) { al += be * pa; be *= pb; }
        }
        ac[5] = (float)al; bc[5] = (float)be;  // row_bcast:31 -> rows 2,3
        {
            double pa = __shfl(al, 31, 64);
            double pb = __shfl(be, 31, 64);
            if (lane >= 32) { al += be * pa; be *= pb; }
        }
    }
    // ---- Bd = (I - cA)^-1 P, solved once in fp64 (wave affine scan)
    {
        double A = aL, B = bL;
#pragma unroll
        for (int d = 1; d < 64; d <<= 1) {
            double pA = __shfl_up(A, d, 64);
            double pB = __shfl_up(B, d, 64);
            if (lane >= d) { B = A * pB + B; A *= pA; }
        }
        double sIn = __shfl_up(B, 1, 64);
        double s = lane ? sIn : 0.0;
#pragma unroll
        for (int j = 0; j < 8; ++j) {
            int i = lane * 8 + j;
            double Pd = sqrt(1.0 + 2.0 * (double)i);
            double fd = 1.0 / (1.0 + cd * (double)(i + 1));
            double ad = (1.0 - cd * (double)i) * fd;
            Bd2[j] = (float)(F * (Pd - cd * Pd * s) * fd);
            s = ad * s + Pd * Pd * fd;
        }
    }

    v2 h[8];
#pragma unroll
    for (int j = 0; j < 8; ++j) h[j] = sp(0.f);

    float y0s = 0.f;              // DEL*(C0.h1), lags one step; 0 keeps h2 == 0
    float u1 = xs[wave][0];       // pre-scaled by DEL

#pragma unroll 2
    for (int k = 0; k < SEQL + 1; ++k) {
        float u_next = xs[wave][k + 1];   // padded, no clamp needed
        v2 du; du.x = u1; du.y = y0s;

        // ---- pass 1: per-lane local (r,s); store inner (scaled) and sb
        v2 inner[8], sb[8];
        v2 r = sp(0.f), s = sp(0.f);
#pragma unroll
        for (int j = 0; j < 8; ++j) {
            v2 hj = h[j];
            v2 in_ = vfma(sp(mE2[j]), r, sp(G2[j]) * hj);
            inner[j] = in_;
            sb[j] = s;
            s = vfma(sp(a_[j]), s, sp(Ps[j]) * in_);   // z = Ps*inner (exact)
            r = vfma(sp(P[j]), hj, r);
        }

        // ---- wave affine scan: single-use DPPs (foldable to v_*_f32_dpp)
#define LVL(CTRL, RM, L) {                                                   \
        s.x = fmaf(bc[L], dpp0<CTRL, RM>(s.x),                               \
                   fmaf(ac[L], dpp0<CTRL, RM>(r.x), s.x));                   \
        s.y = fmaf(bc[L], dpp0<CTRL, RM>(s.y),                               \
                   fmaf(ac[L], dpp0<CTRL, RM>(r.y), s.y));                   \
        r.x += dpp0<CTRL, RM>(r.x);                                          \
        r.y += dpp0<CTRL, RM>(r.y); }
        LVL(0x111, 0xF, 0)   // row_shr:1
        LVL(0x112, 0xF, 1)   // row_shr:2
        LVL(0x114, 0xF, 2)   // row_shr:4
        LVL(0x118, 0xF, 3)   // row_shr:8
        LVL(0x142, 0xA, 4)   // row_bcast:15 -> rows 1,3
        LVL(0x143, 0xC, 5)   // row_bcast:31 -> rows 2,3
#undef LVL
        v2 ri, si;           // exclusive: state entering this lane (lane0 = 0)
        ri.x = dpp0<0x138, 0xF>(r.x);  ri.y = dpp0<0x138, 0xF>(r.y);
        si.x = dpp0<0x138, 0xF>(s.x);  si.y = dpp0<0x138, 0xF>(s.y);

        // ---- pass 2: yy = inner + mE2*sb + K2*ri + K1*si + Bd2*du (scaled),
        //              tanh = 1 - 2/(2^yy + 1)
        float part = 0.f;
#pragma unroll
        for (int j = 0; j < 8; ++j) {
            v2 yy = vfma(sp(mE2[j]), sb[j], inner[j]);
            yy = vfma(sp(K2[j]), ri, yy);
            yy = vfma(sp(K1[j]), si, yy);
            yy = vfma(sp(Bd2[j]), du, yy);
            v2 e;  e.x = __builtin_amdgcn_exp2f(yy.x);
                   e.y = __builtin_amdgcn_exp2f(yy.y);
            v2 e1 = e + sp(1.f);
            v2 rc; rc.x = __builtin_amdgcn_rcpf(e1.x);
                   rc.y = __builtin_amdgcn_rcpf(e1.y);
            v2 hn = vfma(sp(-2.f), rc, sp(1.f));
            h[j] = hn;
            part = fmaf(C0d[j], hn.x, part);
        }
        // y0 = DEL*(C0 . h1_new): consumed only in NEXT step's pass 2 -> slack
        part += dpp0<0x111, 0xF>(part);
        part += dpp0<0x112, 0xF>(part);
        part += dpp0<0x114, 0xF>(part);
        part += dpp0<0x118, 0xF>(part);
        part += dpp0<0x142, 0xA>(part);
        part += dpp0<0x143, 0xC>(part);
        y0s = __builtin_bit_cast(float,
                __builtin_amdgcn_readlane(__builtin_bit_cast(int, part), 63));
        u1 = u_next;
    }

    // ---- epilogue: logits[row] = h2_final @ M + b
    __syncthreads();
    for (int idx = tid; idx < HIDN * OUTD; idx += 256) Ms[idx] = Mmat[idx];
    __syncthreads();

    float acc[OUTD];
#pragma unroll
    for (int o = 0; o < OUTD; ++o) acc[o] = 0.f;
#pragma unroll
    for (int j = 0; j < 8; ++j) {
        float hv = h[j].y;
        int i = lane * 8 + j;
#pragma unroll
        for (int o = 0; o < OUTD; ++o) acc[o] = fmaf(hv, Ms[i * OUTD + o], acc[o]);
    }
#pragma unroll
    for (int o = 0; o < OUTD; ++o) {
#pragma unroll
        for (int d = 32; d; d >>= 1) acc[o] += __shfl_xor(acc[o], d, 64);
    }
    if (lane == 0) {
#pragma unroll
        for (int o = 0; o < OUTD; ++o) out[row * OUTD + o] = acc[o] + bias[o];
    }
}

extern "C" void kernel_launch(void* const* d_in, const int* in_sizes, int n_in,
                              void* d_out, int out_size, void* d_ws, size_t ws_size,
                              hipStream_t stream) {
    const float* x  = (const float*)d_in[0];  // (1024, 784)
    const float* C0 = (const float*)d_in[1];  // (1, 512)
    const float* C1 = (const float*)d_in[2];  // (512, 512)
    const float* W  = (const float*)d_in[3];  // (512, 10)
    const float* b  = (const float*)d_in[4];  // (10,)
    float* M = (float*)d_ws;                  // 512*10 fp32 scratch

    compute_M<<<dim3(8), dim3(256), 0, stream>>>(C1, W, M);
    ssm_main<<<dim3(256), dim3(256), 0, stream>>>(x, C0, M, b, (float*)d_out);
}